// Round 4
// baseline (740.542 us; speedup 1.0000x reference)
//
#include <hip/hip_runtime.h>

// BSQ forward: x (65536x512 f32) -> z (x16) -> sign bits -> decode (x512).
// Normalize is sign-invariant -> skipped; STE forward output == sign(z).
//
// NUMERICS (verified round 3, absmax 7.8e-3): emulate np.einsum's
// SSE-baseline sum-of-products BITWISE:
//   4 partials, partial j accumulates d === j (mod 4);
//   chunks of 16, REVERSED subvector chain (d=16i+12+j hits accumulator
//   first), separate __fmul_rn/__fadd_rn (baseline has NO FMA);
//   reduce (p0+p1)+(p2+p3); + b_enc as separate f32 add.
//
// ROUND 4 CHANGE (DS-pipe-bound fix): lane = 4c+j owns channel c, partial j.
// W slice per lane = 128 floats -> 32 float4 REGISTERS, loaded once
// (eliminates per-token W LDS reads, half the DS traffic). x staged
// transposed-by-j so each 16-chunk is ONE ds_read_b128 (16-lane broadcast).

constexpr int DIM  = 512;
constexpr int NC   = 16;
constexpr int TPB  = 64;     // tokens per block (16 per wave)
constexpr int NTOK = 65536;

__device__ __forceinline__ float mul_rn(float a, float b) { return __fmul_rn(a, b); }
__device__ __forceinline__ float add_rn(float a, float b) { return __fadd_rn(a, b); }

__global__ __launch_bounds__(256, 2) void bsq_main(
    const float* __restrict__ x,
    const float* __restrict__ Wenc,   // (16, 512)
    const float* __restrict__ benc,   // (16,)
    const float* __restrict__ Wdec,   // (512, 16)
    const float* __restrict__ bdec,   // (512,)
    float* __restrict__ out)          // (65536, 512)
{
    __shared__ float    s_wt[NC * DIM];    // 32 KB: W transposed by j (one-time)
    __shared__ float    s_xt[4][4 * DIM];  // 32 KB: per-wave slab, 4 tokens transposed
    __shared__ unsigned s_code[TPB];

    const int tid  = threadIdx.x;
    const int lane = tid & 63;
    const int wv   = tid >> 6;      // wave 0..3, owns 16 tokens
    const int c    = lane >> 2;     // channel 0..15
    const int j    = lane & 3;      // partial index (d mod 4)
    const size_t tok0 = (size_t)blockIdx.x * TPB;

    // ---- one-time: stage W transposed, pull this lane's slice into registers ----
    {
        const float4* wg = (const float4*)Wenc;
#pragma unroll
        for (int q = 0; q < 8; ++q) {
            int idx = q * 256 + tid;        // 0..2047
            int cc  = idx >> 7;             // channel
            int m   = idx & 127;            // d/4
            float4 v = wg[idx];             // w[cc][4m .. 4m+3]
            s_wt[cc * 512 +   0 + m] = v.x;
            s_wt[cc * 512 + 128 + m] = v.y;
            s_wt[cc * 512 + 256 + m] = v.z;
            s_wt[cc * 512 + 384 + m] = v.w;
        }
    }
    __syncthreads();
    float4 Wr[32];                          // w[c][4m+j], m = 4i..4i+3
#pragma unroll
    for (int i = 0; i < 32; ++i)
        Wr[i] = *(const float4*)&s_wt[c * 512 + j * 128 + 4 * i];
    const float bc = benc[c];

    // ---- encode: wave processes 16 tokens in 4 rounds of 4 ----
    const float4* xg = (const float4*)(x + (tok0 + (size_t)wv * 16) * DIM);

    float4 pf[8];                           // round prefetch: 4 tokens = 512 float4
#pragma unroll
    for (int q = 0; q < 8; ++q) pf[q] = xg[q * 64 + lane];

    for (int r = 0; r < 4; ++r) {
        // transpose-write prefetched 4 tokens into this wave's slab
#pragma unroll
        for (int q = 0; q < 8; ++q) {
            int idx = q * 64 + lane;        // 0..511
            int tt  = idx >> 7;             // token-in-round
            int m   = idx & 127;
            float4 v = pf[q];               // x[tt][4m..4m+3]
            s_xt[wv][tt * 512 +   0 + m] = v.x;
            s_xt[wv][tt * 512 + 128 + m] = v.y;
            s_xt[wv][tt * 512 + 256 + m] = v.z;
            s_xt[wv][tt * 512 + 384 + m] = v.w;
        }
        if (r < 3) {                        // issue next round's global loads now
            const float4* nx = xg + (r + 1) * 512;
#pragma unroll
            for (int q = 0; q < 8; ++q) pf[q] = nx[q * 64 + lane];
        }
        // wave-private slab: drain DS writes, wave-lockstep barrier (no syncthreads)
        asm volatile("s_waitcnt lgkmcnt(0)" ::: "memory");
        __builtin_amdgcn_wave_barrier();

        // 4 independent chains (one per token) interleaved for ILP
        float p0 = 0.f, p1 = 0.f, p2 = 0.f, p3 = 0.f;
        const float* xp = &s_xt[wv][j * 128];
#pragma unroll
        for (int i = 0; i < 32; ++i) {
            float4 x0 = *(const float4*)(xp +    0 + 4 * i);
            float4 x1 = *(const float4*)(xp +  512 + 4 * i);
            float4 x2 = *(const float4*)(xp + 1024 + 4 * i);
            float4 x3 = *(const float4*)(xp + 1536 + 4 * i);
            float4 w4 = Wr[i];
            // numpy chunk: d=16i+12+j first, then +8, +4, +0 (reversed chain)
            p0 = add_rn(mul_rn(x0.w, w4.w), p0);
            p1 = add_rn(mul_rn(x1.w, w4.w), p1);
            p2 = add_rn(mul_rn(x2.w, w4.w), p2);
            p3 = add_rn(mul_rn(x3.w, w4.w), p3);
            p0 = add_rn(mul_rn(x0.z, w4.z), p0);
            p1 = add_rn(mul_rn(x1.z, w4.z), p1);
            p2 = add_rn(mul_rn(x2.z, w4.z), p2);
            p3 = add_rn(mul_rn(x3.z, w4.z), p3);
            p0 = add_rn(mul_rn(x0.y, w4.y), p0);
            p1 = add_rn(mul_rn(x1.y, w4.y), p1);
            p2 = add_rn(mul_rn(x2.y, w4.y), p2);
            p3 = add_rn(mul_rn(x3.y, w4.y), p3);
            p0 = add_rn(mul_rn(x0.x, w4.x), p0);
            p1 = add_rn(mul_rn(x1.x, w4.x), p1);
            p2 = add_rn(mul_rn(x2.x, w4.x), p2);
            p3 = add_rn(mul_rn(x3.x, w4.x), p3);
        }
        // per token: hadd tree across j lanes, +b_enc, ballot, keep bit from lane 4c
        float pt[4] = {p0, p1, p2, p3};
#pragma unroll
        for (int tt = 0; tt < 4; ++tt) {
            float s = add_rn(pt[tt], __shfl_xor(pt[tt], 1));
            float z = add_rn(s, __shfl_xor(s, 2));
            z = add_rn(z, bc);
            unsigned long long m = __ballot(z >= 0.0f);   // channel c's bit at lane 4c
            if (lane == 0) {
                unsigned code = 0;
#pragma unroll
                for (int cc = 0; cc < NC; ++cc)
                    code |= (unsigned)((m >> (4 * cc)) & 1ull) << cc;
                s_code[wv * 16 + r * 4 + tt] = code;
            }
        }
    }
    __syncthreads();

    // ---- decode: thread owns output columns 2*tid, 2*tid+1 (verified r3) ----
    float wa[NC], wb[NC];
    {
        const float4* wrow = (const float4*)(Wdec + tid * 32);
#pragma unroll
        for (int p = 0; p < 4; ++p) {
            float4 v = wrow[p];
            wa[p * 4 + 0] = v.x; wa[p * 4 + 1] = v.y;
            wa[p * 4 + 2] = v.z; wa[p * 4 + 3] = v.w;
        }
#pragma unroll
        for (int p = 0; p < 4; ++p) {
            float4 v = wrow[4 + p];
            wb[p * 4 + 0] = v.x; wb[p * 4 + 1] = v.y;
            wb[p * 4 + 2] = v.z; wb[p * 4 + 3] = v.w;
        }
    }
    const float2 bdv = *(const float2*)(bdec + 2 * tid);
    float* op = out + tok0 * DIM + 2 * tid;

    int cv = (int)s_code[lane];             // lane l holds block-token l's code
#pragma unroll 4
    for (int t2 = 0; t2 < TPB; ++t2) {
        unsigned code = (unsigned)__builtin_amdgcn_readlane(cv, t2);  // wave-uniform
        float o0 = bdv.x, o1 = bdv.y;
#pragma unroll
        for (int cc = 0; cc < NC; ++cc) {
            float s = ((code >> cc) & 1u) ? 1.0f : -1.0f;   // scalar cselect
            o0 = fmaf(wa[cc], s, o0);
            o1 = fmaf(wb[cc], s, o1);
        }
        *(float2*)(op + (size_t)t2 * DIM) = make_float2(o0, o1);      // coalesced
    }
}

extern "C" void kernel_launch(void* const* d_in, const int* in_sizes, int n_in,
                              void* d_out, int out_size, void* d_ws, size_t ws_size,
                              hipStream_t stream) {
    const float* x    = (const float*)d_in[0];
    const float* Wenc = (const float*)d_in[1];
    const float* benc = (const float*)d_in[2];
    const float* Wdec = (const float*)d_in[3];
    const float* bdec = (const float*)d_in[4];
    float* out = (float*)d_out;

    bsq_main<<<dim3(NTOK / TPB), dim3(256), 0, stream>>>(x, Wenc, benc, Wdec, bdec, out);
}

// Round 5
// 472.669 us; speedup vs baseline: 1.5667x; 1.5667x over previous
//
#include <hip/hip_runtime.h>

// BSQ forward: x (65536x512 f32) -> z (x16) -> sign bits -> decode (x512).
// Normalize is sign-invariant -> skipped; STE forward output == sign(z).
//
// NUMERICS (verified rounds 3+4, absmax 7.8e-3 = decode rounding only):
// emulate np.einsum's SSE-baseline sum-of-products BITWISE:
//   4 partials, partial j accumulates d === j (mod 4);
//   chunks of 16, REVERSED subvector chain (d=16i+12+j hits accumulator
//   first), separate __fmul_rn/__fadd_rn (baseline has NO FMA);
//   reduce (p0+p1)+(p2+p3); + b_enc as separate f32 add.
//
// ROUND 5 CHANGE: round 4's W-in-registers design spilled to scratch
// (VGPR_Count pinned at 128 by __launch_bounds__(256,2) -> 1.9 GB scratch
// traffic, 620 us). Fix: __launch_bounds__(256,1) (VGPR cap 512, live set
// ~190 -> no spill, ~2 waves/EU) and union the one-time W-transpose LDS
// with the x slabs (64 KB -> 32 KB so LDS doesn't cap occupancy).

constexpr int DIM  = 512;
constexpr int NC   = 16;
constexpr int TPB  = 64;     // tokens per block (16 per wave)
constexpr int NTOK = 65536;

__device__ __forceinline__ float mul_rn(float a, float b) { return __fmul_rn(a, b); }
__device__ __forceinline__ float add_rn(float a, float b) { return __fadd_rn(a, b); }

__global__ __launch_bounds__(256, 1) void bsq_main(
    const float* __restrict__ x,
    const float* __restrict__ Wenc,   // (16, 512)
    const float* __restrict__ benc,   // (16,)
    const float* __restrict__ Wdec,   // (512, 16)
    const float* __restrict__ bdec,   // (512,)
    float* __restrict__ out)          // (65536, 512)
{
    // Phase 0 uses wt (W transposed-by-j, one-time); phase 1 reuses the same
    // 32 KB as per-wave x slabs. Second __syncthreads guards the overwrite.
    __shared__ union {
        float wt[NC * DIM];      // 32 KB
        float xt[4][4 * DIM];    // 32 KB: per-wave slab, 4 tokens transposed
    } s;
    __shared__ unsigned s_code[TPB];

    const int tid  = threadIdx.x;
    const int lane = tid & 63;
    const int wv   = tid >> 6;      // wave 0..3, owns 16 tokens
    const int c    = lane >> 2;     // channel 0..15
    const int j    = lane & 3;      // partial index (d mod 4)
    const size_t tok0 = (size_t)blockIdx.x * TPB;

    // ---- one-time: stage W transposed, pull this lane's slice into registers ----
    {
        const float4* wg = (const float4*)Wenc;
#pragma unroll
        for (int q = 0; q < 8; ++q) {
            int idx = q * 256 + tid;        // 0..2047
            int cc  = idx >> 7;             // channel
            int m   = idx & 127;            // d/4
            float4 v = wg[idx];             // w[cc][4m .. 4m+3]
            s.wt[cc * 512 +   0 + m] = v.x;
            s.wt[cc * 512 + 128 + m] = v.y;
            s.wt[cc * 512 + 256 + m] = v.z;
            s.wt[cc * 512 + 384 + m] = v.w;
        }
    }
    __syncthreads();
    float4 Wr[32];                          // w[c][4m+j], m = 4i..4i+3
#pragma unroll
    for (int i = 0; i < 32; ++i)
        Wr[i] = *(const float4*)&s.wt[c * 512 + j * 128 + 4 * i];
    const float bc = benc[c];
    __syncthreads();                        // wt dead; xt may now be written

    // ---- encode: wave processes 16 tokens in 4 rounds of 4 ----
    const float4* xg = (const float4*)(x + (tok0 + (size_t)wv * 16) * DIM);

    float4 pf[8];                           // round prefetch: 4 tokens = 512 float4
#pragma unroll
    for (int q = 0; q < 8; ++q) pf[q] = xg[q * 64 + lane];

    for (int r = 0; r < 4; ++r) {
        // transpose-write prefetched 4 tokens into this wave's slab
#pragma unroll
        for (int q = 0; q < 8; ++q) {
            int idx = q * 64 + lane;        // 0..511
            int tt  = idx >> 7;             // token-in-round
            int m   = idx & 127;
            float4 v = pf[q];               // x[tt][4m..4m+3]
            s.xt[wv][tt * 512 +   0 + m] = v.x;
            s.xt[wv][tt * 512 + 128 + m] = v.y;
            s.xt[wv][tt * 512 + 256 + m] = v.z;
            s.xt[wv][tt * 512 + 384 + m] = v.w;
        }
        if (r < 3) {                        // issue next round's global loads now
            const float4* nx = xg + (r + 1) * 512;
#pragma unroll
            for (int q = 0; q < 8; ++q) pf[q] = nx[q * 64 + lane];
        }
        // wave-private slab: drain DS writes, wave-lockstep barrier (no syncthreads)
        asm volatile("s_waitcnt lgkmcnt(0)" ::: "memory");
        __builtin_amdgcn_wave_barrier();

        // 4 independent chains (one per token) interleaved for ILP
        float p0 = 0.f, p1 = 0.f, p2 = 0.f, p3 = 0.f;
        const float* xp = &s.xt[wv][j * 128];
#pragma unroll
        for (int i = 0; i < 32; ++i) {
            float4 x0 = *(const float4*)(xp +    0 + 4 * i);
            float4 x1 = *(const float4*)(xp +  512 + 4 * i);
            float4 x2 = *(const float4*)(xp + 1024 + 4 * i);
            float4 x3 = *(const float4*)(xp + 1536 + 4 * i);
            float4 w4 = Wr[i];
            // numpy chunk: d=16i+12+j first, then +8, +4, +0 (reversed chain)
            p0 = add_rn(mul_rn(x0.w, w4.w), p0);
            p1 = add_rn(mul_rn(x1.w, w4.w), p1);
            p2 = add_rn(mul_rn(x2.w, w4.w), p2);
            p3 = add_rn(mul_rn(x3.w, w4.w), p3);
            p0 = add_rn(mul_rn(x0.z, w4.z), p0);
            p1 = add_rn(mul_rn(x1.z, w4.z), p1);
            p2 = add_rn(mul_rn(x2.z, w4.z), p2);
            p3 = add_rn(mul_rn(x3.z, w4.z), p3);
            p0 = add_rn(mul_rn(x0.y, w4.y), p0);
            p1 = add_rn(mul_rn(x1.y, w4.y), p1);
            p2 = add_rn(mul_rn(x2.y, w4.y), p2);
            p3 = add_rn(mul_rn(x3.y, w4.y), p3);
            p0 = add_rn(mul_rn(x0.x, w4.x), p0);
            p1 = add_rn(mul_rn(x1.x, w4.x), p1);
            p2 = add_rn(mul_rn(x2.x, w4.x), p2);
            p3 = add_rn(mul_rn(x3.x, w4.x), p3);
        }
        // per token: hadd tree across j lanes, +b_enc, ballot, bit from lane 4c
        float pt[4] = {p0, p1, p2, p3};
#pragma unroll
        for (int tt = 0; tt < 4; ++tt) {
            float sh = add_rn(pt[tt], __shfl_xor(pt[tt], 1));
            float z  = add_rn(sh, __shfl_xor(sh, 2));
            z = add_rn(z, bc);
            unsigned long long m = __ballot(z >= 0.0f);   // channel c's bit at lane 4c
            if (lane == 0) {
                unsigned code = 0;
#pragma unroll
                for (int cc = 0; cc < NC; ++cc)
                    code |= (unsigned)((m >> (4 * cc)) & 1ull) << cc;
                s_code[wv * 16 + r * 4 + tt] = code;
            }
        }
    }
    __syncthreads();

    // ---- decode: thread owns output columns 2*tid, 2*tid+1 (verified r3/r4) ----
    float wa[NC], wb[NC];
    {
        const float4* wrow = (const float4*)(Wdec + tid * 32);
#pragma unroll
        for (int p = 0; p < 4; ++p) {
            float4 v = wrow[p];
            wa[p * 4 + 0] = v.x; wa[p * 4 + 1] = v.y;
            wa[p * 4 + 2] = v.z; wa[p * 4 + 3] = v.w;
        }
#pragma unroll
        for (int p = 0; p < 4; ++p) {
            float4 v = wrow[4 + p];
            wb[p * 4 + 0] = v.x; wb[p * 4 + 1] = v.y;
            wb[p * 4 + 2] = v.z; wb[p * 4 + 3] = v.w;
        }
    }
    const float2 bdv = *(const float2*)(bdec + 2 * tid);
    float* op = out + tok0 * DIM + 2 * tid;

    int cv = (int)s_code[lane];             // lane l holds block-token l's code
#pragma unroll 4
    for (int t2 = 0; t2 < TPB; ++t2) {
        unsigned code = (unsigned)__builtin_amdgcn_readlane(cv, t2);  // wave-uniform
        float o0 = bdv.x, o1 = bdv.y;
#pragma unroll
        for (int cc = 0; cc < NC; ++cc) {
            float sgn = ((code >> cc) & 1u) ? 1.0f : -1.0f;   // scalar cselect
            o0 = fmaf(wa[cc], sgn, o0);
            o1 = fmaf(wb[cc], sgn, o1);
        }
        *(float2*)(op + (size_t)t2 * DIM) = make_float2(o0, o1);      // coalesced
    }
}

extern "C" void kernel_launch(void* const* d_in, const int* in_sizes, int n_in,
                              void* d_out, int out_size, void* d_ws, size_t ws_size,
                              hipStream_t stream) {
    const float* x    = (const float*)d_in[0];
    const float* Wenc = (const float*)d_in[1];
    const float* benc = (const float*)d_in[2];
    const float* Wdec = (const float*)d_in[3];
    const float* bdec = (const float*)d_in[4];
    float* out = (float*)d_out;

    bsq_main<<<dim3(NTOK / TPB), dim3(256), 0, stream>>>(x, Wenc, benc, Wdec, bdec, out);
}